// Round 6
// baseline (702.263 us; speedup 1.0000x reference)
//
#include <hip/hip_runtime.h>

#define DIM 128
#define BN_EPS 1e-5f
#define NBUCK 512

typedef short short8 __attribute__((ext_vector_type(8)));   // 8 bf16 bit patterns
typedef float floatx4 __attribute__((ext_vector_type(4)));

__device__ __forceinline__ unsigned short f2bf(float f) {
    unsigned int u = __builtin_bit_cast(unsigned int, f);
    u += 0x7FFFu + ((u >> 16) & 1u);          // RNE (inputs are finite)
    return (unsigned short)(u >> 16);
}
__device__ __forceinline__ float bf2f(unsigned short h) {
    return __builtin_bit_cast(float, (unsigned int)h << 16);
}

// ---------------- degree ----------------

__global__ void deg_kernel(const int* __restrict__ row, int* __restrict__ deg, int E) {
    int e = blockIdx.x * blockDim.x + threadIdx.x;
    if (e < E) atomicAdd(&deg[row[e]], 1);
}

// ---------------- scan blocks + dis + degree histogram ----------------
// 1024 nodes per 256-thread block. Also writes dis[i]=rsqrt(deg+1) and
// accumulates a degree histogram (LDS-staged, one flush per block).

__global__ __launch_bounds__(256) void scan_block_kernel(const int* __restrict__ deg,
                                                         int* __restrict__ rowptr,
                                                         int* __restrict__ aux,
                                                         float* __restrict__ dis,
                                                         int* __restrict__ hist, int n) {
    __shared__ int ls[256];
    __shared__ int lh[NBUCK];
    const int base = blockIdx.x * 1024;
    const int t = threadIdx.x;
    lh[t] = 0; lh[t + 256] = 0;
    int v[4]; int s = 0;
    #pragma unroll
    for (int k = 0; k < 4; ++k) {
        int i = base + t * 4 + k;
        v[k] = (i < n) ? deg[i] : 0;
        s += v[k];
    }
    ls[t] = s;
    __syncthreads();
    #pragma unroll
    for (int k = 0; k < 4; ++k) {
        int i = base + t * 4 + k;
        if (i < n) {
            dis[i] = rsqrtf((float)(v[k] + 1));   // +1 self-loop
            atomicAdd(&lh[min(v[k], NBUCK - 1)], 1);
        }
    }
    for (int off = 1; off < 256; off <<= 1) {
        int x = (t >= off) ? ls[t - off] : 0;
        __syncthreads();
        ls[t] += x;
        __syncthreads();
    }
    int excl = ls[t] - s;
    if (t == 255) aux[blockIdx.x] = ls[255];
    #pragma unroll
    for (int k = 0; k < 4; ++k) {
        int i = base + t * 4 + k;
        if (i < n) rowptr[i] = excl;
        excl += v[k];
    }
    __syncthreads();
    if (lh[t])       atomicAdd(&hist[t],       lh[t]);
    if (lh[t + 256]) atomicAdd(&hist[t + 256], lh[t + 256]);
}

// serial: scan aux (edge-offset per 1024-block) + scan hist -> histbase
__global__ void scan_aux_kernel(int* __restrict__ aux, int nb, int* __restrict__ rowptr,
                                int n, int E, const int* __restrict__ hist,
                                int* __restrict__ histbase) {
    int s = 0;
    for (int i = 0; i < nb; ++i) { int v = aux[i]; aux[i] = s; s += v; }
    rowptr[n] = E;
    s = 0;
    for (int i = 0; i < NBUCK; ++i) { int v = hist[i]; histbase[i] = s; s += v; }
}

// finalize rowptr (+block offset) and build degree-sorted permutation
__global__ void finalize_nodes_kernel(int* __restrict__ rowptr, const int* __restrict__ aux,
                                      const int* __restrict__ deg, int* __restrict__ histbase,
                                      int* __restrict__ perm, int n) {
    int i = blockIdx.x * blockDim.x + threadIdx.x;
    if (i >= n) return;
    rowptr[i] += aux[i >> 10];
    int b = min(deg[i], NBUCK - 1);
    int pos = atomicAdd(&histbase[b], 1);
    perm[pos] = i;
}

// ---------------- scatter edges into CSR buckets: one 8B (col, norm) write ----

__global__ void scatter_kernel(const int* __restrict__ row, const int* __restrict__ col,
                               const float* __restrict__ dis, const int* __restrict__ rowptr,
                               int* __restrict__ cursor, int2* __restrict__ epack, int E) {
    int e = blockIdx.x * blockDim.x + threadIdx.x;
    if (e >= E) return;
    int r = row[e], c = col[e];
    int pos = rowptr[r] + atomicAdd(&cursor[r], 1);
    float nrm = dis[r] * dis[c];
    epack[pos] = make_int2(c, __builtin_bit_cast(int, nrm));
}

// ---------------- W -> bf16 B-fragment order ----------------
// wfrag[((kt*8+nt)*64 + lane)*8 + j] = W[kt*32 + (lane>>4)*8 + j][nt*16 + (lane&15)]

__global__ void convert_w_kernel(const float* __restrict__ W1, const float* __restrict__ W2,
                                 unsigned short* __restrict__ wfrag) {
    int s = blockIdx.x * blockDim.x + threadIdx.x;   // 0..4095
    if (s >= 4096) return;
    int m  = s >> 11;
    int s2 = s & 2047;
    int kt = s2 >> 9;
    int nt = (s2 >> 6) & 7;
    int l  = s2 & 63;
    const float* W = m ? W2 : W1;
    unsigned short* o = wfrag + (size_t)m * 16384 + (size_t)s2 * 8;
    int k0 = kt * 32 + (l >> 4) * 8;
    int n0 = nt * 16 + (l & 15);
    #pragma unroll
    for (int j = 0; j < 8; ++j) o[j] = f2bf(W[(k0 + j) * DIM + n0]);
}

// ---------------- MFMA GEMM, fp32 A input (layer 1, no BN) ----------------

__global__ __launch_bounds__(256) void gemm_mfma_f32_kernel(
    const float* __restrict__ A, const unsigned short* __restrict__ wfrag,
    unsigned short* __restrict__ C, int n)
{
    __shared__ unsigned short sA[64][136];
    const int tid  = threadIdx.x;
    const int row0 = blockIdx.x * 64;

    #pragma unroll
    for (int l = 0; l < 8; ++l) {
        int idx = tid + l * 256;
        int r   = idx >> 5;
        int c4  = (idx & 31) * 4;
        float4 v;
        if (row0 + r < n) v = *(const float4*)(A + (size_t)(row0 + r) * DIM + c4);
        else              v = make_float4(0.f, 0.f, 0.f, 0.f);
        unsigned int lo = (unsigned int)f2bf(v.x) | ((unsigned int)f2bf(v.y) << 16);
        unsigned int hi = (unsigned int)f2bf(v.z) | ((unsigned int)f2bf(v.w) << 16);
        *(uint2*)(&sA[r][c4]) = make_uint2(lo, hi);
    }
    __syncthreads();

    const int wave = tid >> 6;
    const int lane = tid & 63;
    const int m    = lane & 15;
    const int quad = lane >> 4;
    const int rowA = wave * 16 + m;

    short8 af[4];
    #pragma unroll
    for (int kt = 0; kt < 4; ++kt)
        af[kt] = *(const short8*)(&sA[rowA][kt * 32 + quad * 8]);

    floatx4 acc[8];
    #pragma unroll
    for (int nt = 0; nt < 8; ++nt) acc[nt] = (floatx4){0.f, 0.f, 0.f, 0.f};

    #pragma unroll
    for (int nt = 0; nt < 8; ++nt)
        #pragma unroll
        for (int kt = 0; kt < 4; ++kt) {
            short8 bfr = *(const short8*)(wfrag + ((size_t)(kt * 8 + nt) * 64 + lane) * 8);
            acc[nt] = __builtin_amdgcn_mfma_f32_16x16x32_bf16(af[kt], bfr, acc[nt], 0, 0, 0);
        }

    #pragma unroll
    for (int nt = 0; nt < 8; ++nt)
        #pragma unroll
        for (int r = 0; r < 4; ++r) {
            int rr = row0 + wave * 16 + quad * 4 + r;
            if (rr < n) C[(size_t)rr * DIM + nt * 16 + m] = f2bf(acc[nt][r]);
        }
}

// ---------------- MFMA GEMM, bf16 A input + fused BN/ReLU (layer 2) ----------------

__global__ __launch_bounds__(256) void gemm_mfma_bn_kernel(
    const unsigned short* __restrict__ A, const unsigned short* __restrict__ wfrag,
    unsigned short* __restrict__ C, int n,
    const float* __restrict__ mean, const float* __restrict__ istd,
    const float* __restrict__ gamma, const float* __restrict__ beta)
{
    __shared__ unsigned short sA[64][136];
    const int tid  = threadIdx.x;
    const int row0 = blockIdx.x * 64;

    #pragma unroll
    for (int l = 0; l < 4; ++l) {
        int idx = tid + l * 256;          // 0..1023, 16B chunks
        int r   = idx >> 4;
        int c8  = (idx & 15) * 8;
        uint4 u = make_uint4(0, 0, 0, 0);
        if (row0 + r < n) u = *(const uint4*)(A + (size_t)(row0 + r) * DIM + c8);
        float f[8] = { bf2f((unsigned short)(u.x & 0xffff)), bf2f((unsigned short)(u.x >> 16)),
                       bf2f((unsigned short)(u.y & 0xffff)), bf2f((unsigned short)(u.y >> 16)),
                       bf2f((unsigned short)(u.z & 0xffff)), bf2f((unsigned short)(u.z >> 16)),
                       bf2f((unsigned short)(u.w & 0xffff)), bf2f((unsigned short)(u.w >> 16)) };
        #pragma unroll
        for (int k = 0; k < 8; ++k) {
            int c = c8 + k;
            f[k] = fmaxf(fmaf(gamma[c] * (f[k] - mean[c]), istd[c], beta[c]), 0.f);
        }
        uint4 o;
        o.x = (unsigned int)f2bf(f[0]) | ((unsigned int)f2bf(f[1]) << 16);
        o.y = (unsigned int)f2bf(f[2]) | ((unsigned int)f2bf(f[3]) << 16);
        o.z = (unsigned int)f2bf(f[4]) | ((unsigned int)f2bf(f[5]) << 16);
        o.w = (unsigned int)f2bf(f[6]) | ((unsigned int)f2bf(f[7]) << 16);
        *(uint4*)(&sA[r][c8]) = o;
    }
    __syncthreads();

    const int wave = tid >> 6;
    const int lane = tid & 63;
    const int m    = lane & 15;
    const int quad = lane >> 4;
    const int rowA = wave * 16 + m;

    short8 af[4];
    #pragma unroll
    for (int kt = 0; kt < 4; ++kt)
        af[kt] = *(const short8*)(&sA[rowA][kt * 32 + quad * 8]);

    floatx4 acc[8];
    #pragma unroll
    for (int nt = 0; nt < 8; ++nt) acc[nt] = (floatx4){0.f, 0.f, 0.f, 0.f};

    #pragma unroll
    for (int nt = 0; nt < 8; ++nt)
        #pragma unroll
        for (int kt = 0; kt < 4; ++kt) {
            short8 bfr = *(const short8*)(wfrag + ((size_t)(kt * 8 + nt) * 64 + lane) * 8);
            acc[nt] = __builtin_amdgcn_mfma_f32_16x16x32_bf16(af[kt], bfr, acc[nt], 0, 0, 0);
        }

    #pragma unroll
    for (int nt = 0; nt < 8; ++nt)
        #pragma unroll
        for (int r = 0; r < 4; ++r) {
            int rr = row0 + wave * 16 + quad * 4 + r;
            if (rr < n) C[(size_t)rr * DIM + nt * 16 + m] = f2bf(acc[nt][r]);
        }
}

// ---------------- CSR aggregation over degree-sorted nodes ----------------
// 16 lanes/node, 8 ch/lane (16 B gathers), 4-edge unroll.
// node = perm[slot]: all nodes in a wave have (near-)equal degree -> no divergence.

template <bool OUT_BF16>
__global__ __launch_bounds__(256) void agg_csr_kernel(
    const unsigned short* __restrict__ hw, const float* __restrict__ dis,
    const int* __restrict__ rowptr, const int2* __restrict__ epack,
    const int* __restrict__ perm,
    const float* __restrict__ bias, void* __restrict__ out_, int n)
{
    const int sub  = threadIdx.x >> 4;        // 0..15 node slot in block
    const int l    = threadIdx.x & 15;
    const int slot = blockIdx.x * 16 + sub;
    if (slot >= n) return;
    const int node = perm[slot];
    const int j = l * 8;

    float acc[8];
    {
        const float d = dis[node];
        const float dd = d * d;
        uint4 u = *(const uint4*)(hw + (size_t)node * DIM + j);
        unsigned int uu[4] = {u.x, u.y, u.z, u.w};
        #pragma unroll
        for (int k = 0; k < 4; ++k) {
            acc[2*k]   = bf2f((unsigned short)(uu[k] & 0xffff)) * dd;
            acc[2*k+1] = bf2f((unsigned short)(uu[k] >> 16))    * dd;
        }
    }

    int p  = rowptr[node];
    const int pe = rowptr[node + 1];

    for (; p + 3 < pe; p += 4) {
        int2 e0 = epack[p],     e1 = epack[p + 1];
        int2 e2 = epack[p + 2], e3 = epack[p + 3];
        float w0 = __builtin_bit_cast(float, e0.y);
        float w1 = __builtin_bit_cast(float, e1.y);
        float w2 = __builtin_bit_cast(float, e2.y);
        float w3 = __builtin_bit_cast(float, e3.y);
        uint4 u0 = *(const uint4*)(hw + (size_t)e0.x * DIM + j);
        uint4 u1 = *(const uint4*)(hw + (size_t)e1.x * DIM + j);
        uint4 u2 = *(const uint4*)(hw + (size_t)e2.x * DIM + j);
        uint4 u3 = *(const uint4*)(hw + (size_t)e3.x * DIM + j);
        unsigned int a[4] = {u0.x, u0.y, u0.z, u0.w};
        unsigned int b[4] = {u1.x, u1.y, u1.z, u1.w};
        unsigned int c[4] = {u2.x, u2.y, u2.z, u2.w};
        unsigned int d[4] = {u3.x, u3.y, u3.z, u3.w};
        #pragma unroll
        for (int k = 0; k < 4; ++k) {
            acc[2*k]   = fmaf(bf2f((unsigned short)(a[k] & 0xffff)), w0, acc[2*k]);
            acc[2*k+1] = fmaf(bf2f((unsigned short)(a[k] >> 16)),    w0, acc[2*k+1]);
            acc[2*k]   = fmaf(bf2f((unsigned short)(b[k] & 0xffff)), w1, acc[2*k]);
            acc[2*k+1] = fmaf(bf2f((unsigned short)(b[k] >> 16)),    w1, acc[2*k+1]);
            acc[2*k]   = fmaf(bf2f((unsigned short)(c[k] & 0xffff)), w2, acc[2*k]);
            acc[2*k+1] = fmaf(bf2f((unsigned short)(c[k] >> 16)),    w2, acc[2*k+1]);
            acc[2*k]   = fmaf(bf2f((unsigned short)(d[k] & 0xffff)), w3, acc[2*k]);
            acc[2*k+1] = fmaf(bf2f((unsigned short)(d[k] >> 16)),    w3, acc[2*k+1]);
        }
    }
    for (; p + 1 < pe; p += 2) {
        int2 e0 = epack[p], e1 = epack[p + 1];
        float w0 = __builtin_bit_cast(float, e0.y);
        float w1 = __builtin_bit_cast(float, e1.y);
        uint4 u0 = *(const uint4*)(hw + (size_t)e0.x * DIM + j);
        uint4 u1 = *(const uint4*)(hw + (size_t)e1.x * DIM + j);
        unsigned int a[4] = {u0.x, u0.y, u0.z, u0.w};
        unsigned int b[4] = {u1.x, u1.y, u1.z, u1.w};
        #pragma unroll
        for (int k = 0; k < 4; ++k) {
            acc[2*k]   = fmaf(bf2f((unsigned short)(a[k] & 0xffff)), w0, acc[2*k]);
            acc[2*k+1] = fmaf(bf2f((unsigned short)(a[k] >> 16)),    w0, acc[2*k+1]);
            acc[2*k]   = fmaf(bf2f((unsigned short)(b[k] & 0xffff)), w1, acc[2*k]);
            acc[2*k+1] = fmaf(bf2f((unsigned short)(b[k] >> 16)),    w1, acc[2*k+1]);
        }
    }
    if (p < pe) {
        int2 e = epack[p];
        float w = __builtin_bit_cast(float, e.y);
        uint4 u = *(const uint4*)(hw + (size_t)e.x * DIM + j);
        unsigned int a[4] = {u.x, u.y, u.z, u.w};
        #pragma unroll
        for (int k = 0; k < 4; ++k) {
            acc[2*k]   = fmaf(bf2f((unsigned short)(a[k] & 0xffff)), w, acc[2*k]);
            acc[2*k+1] = fmaf(bf2f((unsigned short)(a[k] >> 16)),    w, acc[2*k+1]);
        }
    }

    float4 b0 = *(const float4*)(bias + j);
    float4 b1 = *(const float4*)(bias + j + 4);
    acc[0] += b0.x; acc[1] += b0.y; acc[2] += b0.z; acc[3] += b0.w;
    acc[4] += b1.x; acc[5] += b1.y; acc[6] += b1.z; acc[7] += b1.w;

    if (OUT_BF16) {
        unsigned short* out = (unsigned short*)out_;
        uint4 o;
        o.x = (unsigned int)f2bf(acc[0]) | ((unsigned int)f2bf(acc[1]) << 16);
        o.y = (unsigned int)f2bf(acc[2]) | ((unsigned int)f2bf(acc[3]) << 16);
        o.z = (unsigned int)f2bf(acc[4]) | ((unsigned int)f2bf(acc[5]) << 16);
        o.w = (unsigned int)f2bf(acc[6]) | ((unsigned int)f2bf(acc[7]) << 16);
        *(uint4*)(out + (size_t)node * DIM + j) = o;
    } else {
        float* out = (float*)out_;
        *(float4*)(out + (size_t)node * DIM + j)     = make_float4(acc[0], acc[1], acc[2], acc[3]);
        *(float4*)(out + (size_t)node * DIM + j + 4) = make_float4(acc[4], acc[5], acc[6], acc[7]);
    }
}

// ---------------- BN column stats over bf16 h1 (16 B loads, 2x unroll) ----------------

__global__ __launch_bounds__(256) void stats_kernel(const unsigned short* __restrict__ h,
                                                    float* __restrict__ stat, int n)
{
    const int tid = threadIdx.x;
    const int cg  = tid & 15;       // channel group: channels cg*8..cg*8+7
    const int rg  = tid >> 4;       // row slot 0..15
    float s[8], q[8];
    #pragma unroll
    for (int k = 0; k < 8; ++k) { s[k] = 0.f; q[k] = 0.f; }

    const int stride = gridDim.x * 16;
    for (int i = blockIdx.x * 16 + rg; i < n; i += 2 * stride) {
        uint4 u0 = *(const uint4*)(h + (size_t)i * DIM + cg * 8);
        int i1 = i + stride;
        uint4 u1 = (i1 < n) ? *(const uint4*)(h + (size_t)i1 * DIM + cg * 8)
                            : make_uint4(0, 0, 0, 0);
        unsigned int a[4] = {u0.x, u0.y, u0.z, u0.w};
        unsigned int b[4] = {u1.x, u1.y, u1.z, u1.w};
        #pragma unroll
        for (int k = 0; k < 4; ++k) {
            float a0 = bf2f((unsigned short)(a[k] & 0xffff));
            float a1 = bf2f((unsigned short)(a[k] >> 16));
            float c0 = bf2f((unsigned short)(b[k] & 0xffff));
            float c1 = bf2f((unsigned short)(b[k] >> 16));
            s[2*k]   += a0 + c0;
            s[2*k+1] += a1 + c1;
            q[2*k]   = fmaf(a0, a0, fmaf(c0, c0, q[2*k]));
            q[2*k+1] = fmaf(a1, a1, fmaf(c1, c1, q[2*k+1]));
        }
    }

    __shared__ float red[16][128];
    #pragma unroll
    for (int k = 0; k < 8; ++k) red[rg][cg * 8 + k] = s[k];
    __syncthreads();
    if (tid < 128) {
        float t = 0.f;
        #pragma unroll
        for (int r = 0; r < 16; ++r) t += red[r][tid];
        atomicAdd(&stat[tid], t);
    }
    __syncthreads();
    #pragma unroll
    for (int k = 0; k < 8; ++k) red[rg][cg * 8 + k] = q[k];
    __syncthreads();
    if (tid < 128) {
        float t = 0.f;
        #pragma unroll
        for (int r = 0; r < 16; ++r) t += red[r][tid];
        atomicAdd(&stat[DIM + tid], t);
    }
}

__global__ void bn_finalize_kernel(const float* __restrict__ stat, float* __restrict__ mi, int n) {
    int j = threadIdx.x;
    if (j < DIM) {
        float mean = stat[j] / (float)n;
        float var  = stat[DIM + j] / (float)n - mean * mean;
        mi[j]       = mean;
        mi[DIM + j] = rsqrtf(var + BN_EPS);
    }
}

// ---------------- launch ----------------

extern "C" void kernel_launch(void* const* d_in, const int* in_sizes, int n_in,
                              void* d_out, int out_size, void* d_ws, size_t ws_size,
                              hipStream_t stream)
{
    const float* x      = (const float*)d_in[0];
    const int*   ei     = (const int*)  d_in[1];
    const float* W1     = (const float*)d_in[2];
    const float* b1     = (const float*)d_in[3];
    const float* gamma1 = (const float*)d_in[4];
    const float* beta1  = (const float*)d_in[5];
    const float* W2     = (const float*)d_in[6];
    const float* b2     = (const float*)d_in[7];
    float* out = (float*)d_out;

    const int N = in_sizes[0] / DIM;   // 100000
    const int E = in_sizes[1] / 2;     // 600000
    const int* row = ei;
    const int* col = ei + E;

    const int NB = (N + 1023) / 1024;

    // Workspace layout (~58 MB), 8B-alignment-safe ordering:
    unsigned short* hw    = (unsigned short*)d_ws;        // N*128 bf16
    unsigned short* h1    = hw + (size_t)N * DIM;         // N*128 bf16
    int2*  epack  = (int2*)(h1 + (size_t)N * DIM);        // E (8B each)
    unsigned short* wfrag = (unsigned short*)(epack + E); // 2*16384 bf16
    float* dis    = (float*)(wfrag + 2 * 16384);          // N
    int*   deg    = (int*)(dis + N);                      // N
    int*   cursor = deg + N;                              // N
    int*   rowptr = cursor + N;                           // N+1
    int*   aux    = rowptr + N + 1;                       // 128
    float* stat   = (float*)(aux + 128);                  // 256
    float* mi     = stat + 256;                           // 256
    int*   perm   = (int*)(mi + 256);                     // N
    int*   hist   = perm + N;                             // NBUCK
    int*   histbase = hist + NBUCK;                       // NBUCK

    hipMemsetAsync(deg,    0, (size_t)N * sizeof(int), stream);
    hipMemsetAsync(cursor, 0, (size_t)N * sizeof(int), stream);
    hipMemsetAsync(stat,   0, 256 * sizeof(float), stream);
    hipMemsetAsync(hist,   0, NBUCK * sizeof(int), stream);

    // Graph structure: degree -> (scan + dis + histogram) -> perm + rowptr -> CSR scatter
    deg_kernel<<<(E + 255) / 256, 256, 0, stream>>>(row, deg, E);
    scan_block_kernel<<<NB, 256, 0, stream>>>(deg, rowptr, aux, dis, hist, N);
    scan_aux_kernel<<<1, 1, 0, stream>>>(aux, NB, rowptr, N, E, hist, histbase);
    finalize_nodes_kernel<<<(N + 255) / 256, 256, 0, stream>>>(rowptr, aux, deg, histbase,
                                                               perm, N);
    scatter_kernel<<<(E + 255) / 256, 256, 0, stream>>>(row, col, dis, rowptr, cursor,
                                                        epack, E);
    convert_w_kernel<<<16, 256, 0, stream>>>(W1, W2, wfrag);

    // Layer 1: hw = bf16(x @ W1) ; h1 = bf16(agg(hw)+self+b1) ; BN stats over h1
    gemm_mfma_f32_kernel<<<(N + 63) / 64, 256, 0, stream>>>(x, wfrag, hw, N);
    agg_csr_kernel<true><<<(N + 15) / 16, 256, 0, stream>>>(hw, dis, rowptr, epack, perm,
                                                            b1, h1, N);
    stats_kernel<<<512, 256, 0, stream>>>(h1, stat, N);
    bn_finalize_kernel<<<1, DIM, 0, stream>>>(stat, mi, N);

    // Layer 2: hw = bf16(relu(BN(h1)) @ W2) ; out = agg(hw)+self+b2 (fp32)
    gemm_mfma_bn_kernel<<<(N + 63) / 64, 256, 0, stream>>>(h1, wfrag + 16384, hw, N,
                                                           mi, mi + DIM, gamma1, beta1);
    agg_csr_kernel<false><<<(N + 15) / 16, 256, 0, stream>>>(hw, dis, rowptr, epack, perm,
                                                             b2, out, N);
}

// Round 7
// 333.444 us; speedup vs baseline: 2.1061x; 2.1061x over previous
//
#include <hip/hip_runtime.h>

#define DIM 128
#define BN_EPS 1e-5f
#define NBUCK 512

typedef short short8 __attribute__((ext_vector_type(8)));   // 8 bf16 bit patterns
typedef float floatx4 __attribute__((ext_vector_type(4)));

__device__ __forceinline__ unsigned short f2bf(float f) {
    unsigned int u = __builtin_bit_cast(unsigned int, f);
    u += 0x7FFFu + ((u >> 16) & 1u);          // RNE (inputs are finite)
    return (unsigned short)(u >> 16);
}
__device__ __forceinline__ float bf2f(unsigned short h) {
    return __builtin_bit_cast(float, (unsigned int)h << 16);
}

// ---------------- degree ----------------

__global__ void deg_kernel(const int* __restrict__ row, int* __restrict__ deg, int E) {
    int e = blockIdx.x * blockDim.x + threadIdx.x;
    if (e < E) atomicAdd(&deg[row[e]], 1);
}

// ---------------- scan blocks + dis + degree histogram ----------------
// 1024 nodes per 256-thread block. Also writes dis[i]=rsqrt(deg+1) and
// accumulates a degree histogram (LDS-staged, one flush per block).

__global__ __launch_bounds__(256) void scan_block_kernel(const int* __restrict__ deg,
                                                         int* __restrict__ rowptr,
                                                         int* __restrict__ aux,
                                                         float* __restrict__ dis,
                                                         int* __restrict__ hist, int n) {
    __shared__ int ls[256];
    __shared__ int lh[NBUCK];
    const int base = blockIdx.x * 1024;
    const int t = threadIdx.x;
    lh[t] = 0; lh[t + 256] = 0;
    int v[4]; int s = 0;
    #pragma unroll
    for (int k = 0; k < 4; ++k) {
        int i = base + t * 4 + k;
        v[k] = (i < n) ? deg[i] : 0;
        s += v[k];
    }
    ls[t] = s;
    __syncthreads();
    #pragma unroll
    for (int k = 0; k < 4; ++k) {
        int i = base + t * 4 + k;
        if (i < n) {
            dis[i] = rsqrtf((float)(v[k] + 1));   // +1 self-loop
            atomicAdd(&lh[min(v[k], NBUCK - 1)], 1);
        }
    }
    for (int off = 1; off < 256; off <<= 1) {
        int x = (t >= off) ? ls[t - off] : 0;
        __syncthreads();
        ls[t] += x;
        __syncthreads();
    }
    int excl = ls[t] - s;
    if (t == 255) aux[blockIdx.x] = ls[255];
    #pragma unroll
    for (int k = 0; k < 4; ++k) {
        int i = base + t * 4 + k;
        if (i < n) rowptr[i] = excl;
        excl += v[k];
    }
    __syncthreads();
    if (lh[t])       atomicAdd(&hist[t],       lh[t]);
    if (lh[t + 256]) atomicAdd(&hist[t + 256], lh[t + 256]);
}

// serial: scan aux (edge-offset per 1024-block) + scan hist -> histbase
__global__ void scan_aux_kernel(int* __restrict__ aux, int nb, int* __restrict__ rowptr,
                                int n, int E, const int* __restrict__ hist,
                                int* __restrict__ histbase) {
    int s = 0;
    for (int i = 0; i < nb; ++i) { int v = aux[i]; aux[i] = s; s += v; }
    rowptr[n] = E;
    s = 0;
    for (int i = 0; i < NBUCK; ++i) { int v = hist[i]; histbase[i] = s; s += v; }
}

// finalize rowptr (+block offset) and build degree-bucketed permutation.
// Contention-free: LDS histogram gives local ranks; ONE global atomic per
// non-empty (block,bucket) reserves a chunk from the bucket cursor.

__global__ __launch_bounds__(256) void finalize_nodes_kernel(
    int* __restrict__ rowptr, const int* __restrict__ aux,
    const int* __restrict__ deg, int* __restrict__ histbase,
    int* __restrict__ perm, int n) {
    __shared__ int lh[NBUCK];     // per-block bucket counts
    __shared__ int lbase[NBUCK];  // reserved chunk base per bucket
    const int base = blockIdx.x * 1024;
    const int t = threadIdx.x;
    lh[t] = 0; lh[t + 256] = 0;
    __syncthreads();
    int b[4], lr[4];
    #pragma unroll
    for (int k = 0; k < 4; ++k) {
        int i = base + t * 4 + k;
        if (i < n) {
            rowptr[i] += aux[i >> 10];
            b[k]  = min(deg[i], NBUCK - 1);
            lr[k] = atomicAdd(&lh[b[k]], 1);      // LDS atomic: local rank
        }
    }
    __syncthreads();
    if (lh[t])       lbase[t]       = atomicAdd(&histbase[t],       lh[t]);
    if (lh[t + 256]) lbase[t + 256] = atomicAdd(&histbase[t + 256], lh[t + 256]);
    __syncthreads();
    #pragma unroll
    for (int k = 0; k < 4; ++k) {
        int i = base + t * 4 + k;
        if (i < n) perm[lbase[b[k]] + lr[k]] = i;
    }
}

// ---------------- scatter edges into CSR buckets: one 8B (col, norm) write ----

__global__ void scatter_kernel(const int* __restrict__ row, const int* __restrict__ col,
                               const float* __restrict__ dis, const int* __restrict__ rowptr,
                               int* __restrict__ cursor, int2* __restrict__ epack, int E) {
    int e = blockIdx.x * blockDim.x + threadIdx.x;
    if (e >= E) return;
    int r = row[e], c = col[e];
    int pos = rowptr[r] + atomicAdd(&cursor[r], 1);
    float nrm = dis[r] * dis[c];
    epack[pos] = make_int2(c, __builtin_bit_cast(int, nrm));
}

// ---------------- W -> bf16 B-fragment order ----------------
// wfrag[((kt*8+nt)*64 + lane)*8 + j] = W[kt*32 + (lane>>4)*8 + j][nt*16 + (lane&15)]

__global__ void convert_w_kernel(const float* __restrict__ W1, const float* __restrict__ W2,
                                 unsigned short* __restrict__ wfrag) {
    int s = blockIdx.x * blockDim.x + threadIdx.x;   // 0..4095
    if (s >= 4096) return;
    int m  = s >> 11;
    int s2 = s & 2047;
    int kt = s2 >> 9;
    int nt = (s2 >> 6) & 7;
    int l  = s2 & 63;
    const float* W = m ? W2 : W1;
    unsigned short* o = wfrag + (size_t)m * 16384 + (size_t)s2 * 8;
    int k0 = kt * 32 + (l >> 4) * 8;
    int n0 = nt * 16 + (l & 15);
    #pragma unroll
    for (int j = 0; j < 8; ++j) o[j] = f2bf(W[(k0 + j) * DIM + n0]);
}

// ---------------- MFMA GEMM, fp32 A input (layer 1, no BN) ----------------

__global__ __launch_bounds__(256) void gemm_mfma_f32_kernel(
    const float* __restrict__ A, const unsigned short* __restrict__ wfrag,
    unsigned short* __restrict__ C, int n)
{
    __shared__ unsigned short sA[64][136];
    const int tid  = threadIdx.x;
    const int row0 = blockIdx.x * 64;

    #pragma unroll
    for (int l = 0; l < 8; ++l) {
        int idx = tid + l * 256;
        int r   = idx >> 5;
        int c4  = (idx & 31) * 4;
        float4 v;
        if (row0 + r < n) v = *(const float4*)(A + (size_t)(row0 + r) * DIM + c4);
        else              v = make_float4(0.f, 0.f, 0.f, 0.f);
        unsigned int lo = (unsigned int)f2bf(v.x) | ((unsigned int)f2bf(v.y) << 16);
        unsigned int hi = (unsigned int)f2bf(v.z) | ((unsigned int)f2bf(v.w) << 16);
        *(uint2*)(&sA[r][c4]) = make_uint2(lo, hi);
    }
    __syncthreads();

    const int wave = tid >> 6;
    const int lane = tid & 63;
    const int m    = lane & 15;
    const int quad = lane >> 4;
    const int rowA = wave * 16 + m;

    short8 af[4];
    #pragma unroll
    for (int kt = 0; kt < 4; ++kt)
        af[kt] = *(const short8*)(&sA[rowA][kt * 32 + quad * 8]);

    floatx4 acc[8];
    #pragma unroll
    for (int nt = 0; nt < 8; ++nt) acc[nt] = (floatx4){0.f, 0.f, 0.f, 0.f};

    #pragma unroll
    for (int nt = 0; nt < 8; ++nt)
        #pragma unroll
        for (int kt = 0; kt < 4; ++kt) {
            short8 bfr = *(const short8*)(wfrag + ((size_t)(kt * 8 + nt) * 64 + lane) * 8);
            acc[nt] = __builtin_amdgcn_mfma_f32_16x16x32_bf16(af[kt], bfr, acc[nt], 0, 0, 0);
        }

    #pragma unroll
    for (int nt = 0; nt < 8; ++nt)
        #pragma unroll
        for (int r = 0; r < 4; ++r) {
            int rr = row0 + wave * 16 + quad * 4 + r;
            if (rr < n) C[(size_t)rr * DIM + nt * 16 + m] = f2bf(acc[nt][r]);
        }
}

// ---------------- MFMA GEMM, bf16 A input + fused BN/ReLU (layer 2) ----------------

__global__ __launch_bounds__(256) void gemm_mfma_bn_kernel(
    const unsigned short* __restrict__ A, const unsigned short* __restrict__ wfrag,
    unsigned short* __restrict__ C, int n,
    const float* __restrict__ mean, const float* __restrict__ istd,
    const float* __restrict__ gamma, const float* __restrict__ beta)
{
    __shared__ unsigned short sA[64][136];
    const int tid  = threadIdx.x;
    const int row0 = blockIdx.x * 64;

    #pragma unroll
    for (int l = 0; l < 4; ++l) {
        int idx = tid + l * 256;          // 0..1023, 16B chunks
        int r   = idx >> 4;
        int c8  = (idx & 15) * 8;
        uint4 u = make_uint4(0, 0, 0, 0);
        if (row0 + r < n) u = *(const uint4*)(A + (size_t)(row0 + r) * DIM + c8);
        float f[8] = { bf2f((unsigned short)(u.x & 0xffff)), bf2f((unsigned short)(u.x >> 16)),
                       bf2f((unsigned short)(u.y & 0xffff)), bf2f((unsigned short)(u.y >> 16)),
                       bf2f((unsigned short)(u.z & 0xffff)), bf2f((unsigned short)(u.z >> 16)),
                       bf2f((unsigned short)(u.w & 0xffff)), bf2f((unsigned short)(u.w >> 16)) };
        #pragma unroll
        for (int k = 0; k < 8; ++k) {
            int c = c8 + k;
            f[k] = fmaxf(fmaf(gamma[c] * (f[k] - mean[c]), istd[c], beta[c]), 0.f);
        }
        uint4 o;
        o.x = (unsigned int)f2bf(f[0]) | ((unsigned int)f2bf(f[1]) << 16);
        o.y = (unsigned int)f2bf(f[2]) | ((unsigned int)f2bf(f[3]) << 16);
        o.z = (unsigned int)f2bf(f[4]) | ((unsigned int)f2bf(f[5]) << 16);
        o.w = (unsigned int)f2bf(f[6]) | ((unsigned int)f2bf(f[7]) << 16);
        *(uint4*)(&sA[r][c8]) = o;
    }
    __syncthreads();

    const int wave = tid >> 6;
    const int lane = tid & 63;
    const int m    = lane & 15;
    const int quad = lane >> 4;
    const int rowA = wave * 16 + m;

    short8 af[4];
    #pragma unroll
    for (int kt = 0; kt < 4; ++kt)
        af[kt] = *(const short8*)(&sA[rowA][kt * 32 + quad * 8]);

    floatx4 acc[8];
    #pragma unroll
    for (int nt = 0; nt < 8; ++nt) acc[nt] = (floatx4){0.f, 0.f, 0.f, 0.f};

    #pragma unroll
    for (int nt = 0; nt < 8; ++nt)
        #pragma unroll
        for (int kt = 0; kt < 4; ++kt) {
            short8 bfr = *(const short8*)(wfrag + ((size_t)(kt * 8 + nt) * 64 + lane) * 8);
            acc[nt] = __builtin_amdgcn_mfma_f32_16x16x32_bf16(af[kt], bfr, acc[nt], 0, 0, 0);
        }

    #pragma unroll
    for (int nt = 0; nt < 8; ++nt)
        #pragma unroll
        for (int r = 0; r < 4; ++r) {
            int rr = row0 + wave * 16 + quad * 4 + r;
            if (rr < n) C[(size_t)rr * DIM + nt * 16 + m] = f2bf(acc[nt][r]);
        }
}

// ---------------- CSR aggregation over degree-bucketed nodes ----------------
// 16 lanes/node, 8 ch/lane (16 B gathers), 4-edge unroll.
// node = perm[slot]: all nodes in a wave have (near-)equal degree -> no divergence.

template <bool OUT_BF16>
__global__ __launch_bounds__(256) void agg_csr_kernel(
    const unsigned short* __restrict__ hw, const float* __restrict__ dis,
    const int* __restrict__ rowptr, const int2* __restrict__ epack,
    const int* __restrict__ perm,
    const float* __restrict__ bias, void* __restrict__ out_, int n)
{
    const int sub  = threadIdx.x >> 4;        // 0..15 node slot in block
    const int l    = threadIdx.x & 15;
    const int slot = blockIdx.x * 16 + sub;
    if (slot >= n) return;
    const int node = perm[slot];
    const int j = l * 8;

    float acc[8];
    {
        const float d = dis[node];
        const float dd = d * d;
        uint4 u = *(const uint4*)(hw + (size_t)node * DIM + j);
        unsigned int uu[4] = {u.x, u.y, u.z, u.w};
        #pragma unroll
        for (int k = 0; k < 4; ++k) {
            acc[2*k]   = bf2f((unsigned short)(uu[k] & 0xffff)) * dd;
            acc[2*k+1] = bf2f((unsigned short)(uu[k] >> 16))    * dd;
        }
    }

    int p  = rowptr[node];
    const int pe = rowptr[node + 1];

    for (; p + 3 < pe; p += 4) {
        int2 e0 = epack[p],     e1 = epack[p + 1];
        int2 e2 = epack[p + 2], e3 = epack[p + 3];
        float w0 = __builtin_bit_cast(float, e0.y);
        float w1 = __builtin_bit_cast(float, e1.y);
        float w2 = __builtin_bit_cast(float, e2.y);
        float w3 = __builtin_bit_cast(float, e3.y);
        uint4 u0 = *(const uint4*)(hw + (size_t)e0.x * DIM + j);
        uint4 u1 = *(const uint4*)(hw + (size_t)e1.x * DIM + j);
        uint4 u2 = *(const uint4*)(hw + (size_t)e2.x * DIM + j);
        uint4 u3 = *(const uint4*)(hw + (size_t)e3.x * DIM + j);
        unsigned int a[4] = {u0.x, u0.y, u0.z, u0.w};
        unsigned int b[4] = {u1.x, u1.y, u1.z, u1.w};
        unsigned int c[4] = {u2.x, u2.y, u2.z, u2.w};
        unsigned int d[4] = {u3.x, u3.y, u3.z, u3.w};
        #pragma unroll
        for (int k = 0; k < 4; ++k) {
            acc[2*k]   = fmaf(bf2f((unsigned short)(a[k] & 0xffff)), w0, acc[2*k]);
            acc[2*k+1] = fmaf(bf2f((unsigned short)(a[k] >> 16)),    w0, acc[2*k+1]);
            acc[2*k]   = fmaf(bf2f((unsigned short)(b[k] & 0xffff)), w1, acc[2*k]);
            acc[2*k+1] = fmaf(bf2f((unsigned short)(b[k] >> 16)),    w1, acc[2*k+1]);
            acc[2*k]   = fmaf(bf2f((unsigned short)(c[k] & 0xffff)), w2, acc[2*k]);
            acc[2*k+1] = fmaf(bf2f((unsigned short)(c[k] >> 16)),    w2, acc[2*k+1]);
            acc[2*k]   = fmaf(bf2f((unsigned short)(d[k] & 0xffff)), w3, acc[2*k]);
            acc[2*k+1] = fmaf(bf2f((unsigned short)(d[k] >> 16)),    w3, acc[2*k+1]);
        }
    }
    for (; p + 1 < pe; p += 2) {
        int2 e0 = epack[p], e1 = epack[p + 1];
        float w0 = __builtin_bit_cast(float, e0.y);
        float w1 = __builtin_bit_cast(float, e1.y);
        uint4 u0 = *(const uint4*)(hw + (size_t)e0.x * DIM + j);
        uint4 u1 = *(const uint4*)(hw + (size_t)e1.x * DIM + j);
        unsigned int a[4] = {u0.x, u0.y, u0.z, u0.w};
        unsigned int b[4] = {u1.x, u1.y, u1.z, u1.w};
        #pragma unroll
        for (int k = 0; k < 4; ++k) {
            acc[2*k]   = fmaf(bf2f((unsigned short)(a[k] & 0xffff)), w0, acc[2*k]);
            acc[2*k+1] = fmaf(bf2f((unsigned short)(a[k] >> 16)),    w0, acc[2*k+1]);
            acc[2*k]   = fmaf(bf2f((unsigned short)(b[k] & 0xffff)), w1, acc[2*k]);
            acc[2*k+1] = fmaf(bf2f((unsigned short)(b[k] >> 16)),    w1, acc[2*k+1]);
        }
    }
    if (p < pe) {
        int2 e = epack[p];
        float w = __builtin_bit_cast(float, e.y);
        uint4 u = *(const uint4*)(hw + (size_t)e.x * DIM + j);
        unsigned int a[4] = {u.x, u.y, u.z, u.w};
        #pragma unroll
        for (int k = 0; k < 4; ++k) {
            acc[2*k]   = fmaf(bf2f((unsigned short)(a[k] & 0xffff)), w, acc[2*k]);
            acc[2*k+1] = fmaf(bf2f((unsigned short)(a[k] >> 16)),    w, acc[2*k+1]);
        }
    }

    float4 b0 = *(const float4*)(bias + j);
    float4 b1 = *(const float4*)(bias + j + 4);
    acc[0] += b0.x; acc[1] += b0.y; acc[2] += b0.z; acc[3] += b0.w;
    acc[4] += b1.x; acc[5] += b1.y; acc[6] += b1.z; acc[7] += b1.w;

    if (OUT_BF16) {
        unsigned short* out = (unsigned short*)out_;
        uint4 o;
        o.x = (unsigned int)f2bf(acc[0]) | ((unsigned int)f2bf(acc[1]) << 16);
        o.y = (unsigned int)f2bf(acc[2]) | ((unsigned int)f2bf(acc[3]) << 16);
        o.z = (unsigned int)f2bf(acc[4]) | ((unsigned int)f2bf(acc[5]) << 16);
        o.w = (unsigned int)f2bf(acc[6]) | ((unsigned int)f2bf(acc[7]) << 16);
        *(uint4*)(out + (size_t)node * DIM + j) = o;
    } else {
        float* out = (float*)out_;
        *(float4*)(out + (size_t)node * DIM + j)     = make_float4(acc[0], acc[1], acc[2], acc[3]);
        *(float4*)(out + (size_t)node * DIM + j + 4) = make_float4(acc[4], acc[5], acc[6], acc[7]);
    }
}

// ---------------- BN column stats over bf16 h1 (16 B loads, 2x unroll) ----------------

__global__ __launch_bounds__(256) void stats_kernel(const unsigned short* __restrict__ h,
                                                    float* __restrict__ stat, int n)
{
    const int tid = threadIdx.x;
    const int cg  = tid & 15;       // channel group: channels cg*8..cg*8+7
    const int rg  = tid >> 4;       // row slot 0..15
    float s[8], q[8];
    #pragma unroll
    for (int k = 0; k < 8; ++k) { s[k] = 0.f; q[k] = 0.f; }

    const int stride = gridDim.x * 16;
    for (int i = blockIdx.x * 16 + rg; i < n; i += 2 * stride) {
        uint4 u0 = *(const uint4*)(h + (size_t)i * DIM + cg * 8);
        int i1 = i + stride;
        uint4 u1 = (i1 < n) ? *(const uint4*)(h + (size_t)i1 * DIM + cg * 8)
                            : make_uint4(0, 0, 0, 0);
        unsigned int a[4] = {u0.x, u0.y, u0.z, u0.w};
        unsigned int b[4] = {u1.x, u1.y, u1.z, u1.w};
        #pragma unroll
        for (int k = 0; k < 4; ++k) {
            float a0 = bf2f((unsigned short)(a[k] & 0xffff));
            float a1 = bf2f((unsigned short)(a[k] >> 16));
            float c0 = bf2f((unsigned short)(b[k] & 0xffff));
            float c1 = bf2f((unsigned short)(b[k] >> 16));
            s[2*k]   += a0 + c0;
            s[2*k+1] += a1 + c1;
            q[2*k]   = fmaf(a0, a0, fmaf(c0, c0, q[2*k]));
            q[2*k+1] = fmaf(a1, a1, fmaf(c1, c1, q[2*k+1]));
        }
    }

    __shared__ float red[16][128];
    #pragma unroll
    for (int k = 0; k < 8; ++k) red[rg][cg * 8 + k] = s[k];
    __syncthreads();
    if (tid < 128) {
        float t = 0.f;
        #pragma unroll
        for (int r = 0; r < 16; ++r) t += red[r][tid];
        atomicAdd(&stat[tid], t);
    }
    __syncthreads();
    #pragma unroll
    for (int k = 0; k < 8; ++k) red[rg][cg * 8 + k] = q[k];
    __syncthreads();
    if (tid < 128) {
        float t = 0.f;
        #pragma unroll
        for (int r = 0; r < 16; ++r) t += red[r][tid];
        atomicAdd(&stat[DIM + tid], t);
    }
}

__global__ void bn_finalize_kernel(const float* __restrict__ stat, float* __restrict__ mi, int n) {
    int j = threadIdx.x;
    if (j < DIM) {
        float mean = stat[j] / (float)n;
        float var  = stat[DIM + j] / (float)n - mean * mean;
        mi[j]       = mean;
        mi[DIM + j] = rsqrtf(var + BN_EPS);
    }
}

// ---------------- launch ----------------

extern "C" void kernel_launch(void* const* d_in, const int* in_sizes, int n_in,
                              void* d_out, int out_size, void* d_ws, size_t ws_size,
                              hipStream_t stream)
{
    const float* x      = (const float*)d_in[0];
    const int*   ei     = (const int*)  d_in[1];
    const float* W1     = (const float*)d_in[2];
    const float* b1     = (const float*)d_in[3];
    const float* gamma1 = (const float*)d_in[4];
    const float* beta1  = (const float*)d_in[5];
    const float* W2     = (const float*)d_in[6];
    const float* b2     = (const float*)d_in[7];
    float* out = (float*)d_out;

    const int N = in_sizes[0] / DIM;   // 100000
    const int E = in_sizes[1] / 2;     // 600000
    const int* row = ei;
    const int* col = ei + E;

    const int NB = (N + 1023) / 1024;

    // Workspace layout (~58 MB), 8B-alignment-safe ordering:
    unsigned short* hw    = (unsigned short*)d_ws;        // N*128 bf16
    unsigned short* h1    = hw + (size_t)N * DIM;         // N*128 bf16
    int2*  epack  = (int2*)(h1 + (size_t)N * DIM);        // E (8B each)
    unsigned short* wfrag = (unsigned short*)(epack + E); // 2*16384 bf16
    float* dis    = (float*)(wfrag + 2 * 16384);          // N
    int*   deg    = (int*)(dis + N);                      // N
    int*   cursor = deg + N;                              // N
    int*   rowptr = cursor + N;                           // N+1
    int*   aux    = rowptr + N + 1;                       // 128
    float* stat   = (float*)(aux + 128);                  // 256
    float* mi     = stat + 256;                           // 256
    int*   perm   = (int*)(mi + 256);                     // N
    int*   hist   = perm + N;                             // NBUCK
    int*   histbase = hist + NBUCK;                       // NBUCK

    hipMemsetAsync(deg,    0, (size_t)N * sizeof(int), stream);
    hipMemsetAsync(cursor, 0, (size_t)N * sizeof(int), stream);
    hipMemsetAsync(stat,   0, 256 * sizeof(float), stream);
    hipMemsetAsync(hist,   0, NBUCK * sizeof(int), stream);

    // Graph structure: degree -> (scan + dis + histogram) -> perm + rowptr -> CSR scatter
    deg_kernel<<<(E + 255) / 256, 256, 0, stream>>>(row, deg, E);
    scan_block_kernel<<<NB, 256, 0, stream>>>(deg, rowptr, aux, dis, hist, N);
    scan_aux_kernel<<<1, 1, 0, stream>>>(aux, NB, rowptr, N, E, hist, histbase);
    finalize_nodes_kernel<<<NB, 256, 0, stream>>>(rowptr, aux, deg, histbase, perm, N);
    scatter_kernel<<<(E + 255) / 256, 256, 0, stream>>>(row, col, dis, rowptr, cursor,
                                                        epack, E);
    convert_w_kernel<<<16, 256, 0, stream>>>(W1, W2, wfrag);

    // Layer 1: hw = bf16(x @ W1) ; h1 = bf16(agg(hw)+self+b1) ; BN stats over h1
    gemm_mfma_f32_kernel<<<(N + 63) / 64, 256, 0, stream>>>(x, wfrag, hw, N);
    agg_csr_kernel<true><<<(N + 15) / 16, 256, 0, stream>>>(hw, dis, rowptr, epack, perm,
                                                            b1, h1, N);
    stats_kernel<<<512, 256, 0, stream>>>(h1, stat, N);
    bn_finalize_kernel<<<1, DIM, 0, stream>>>(stat, mi, N);

    // Layer 2: hw = bf16(relu(BN(h1)) @ W2) ; out = agg(hw)+self+b2 (fp32)
    gemm_mfma_bn_kernel<<<(N + 63) / 64, 256, 0, stream>>>(h1, wfrag + 16384, hw, N,
                                                           mi, mi + DIM, gamma1, beta1);
    agg_csr_kernel<false><<<(N + 15) / 16, 256, 0, stream>>>(hw, dis, rowptr, epack, perm,
                                                             b2, out, N);
}